// Round 7
// baseline (216.847 us; speedup 1.0000x reference)
//
#include <hip/hip_runtime.h>

// x [B=32, C=512, H=64, W=64] fp32
#define NB 32
#define NC 512
#define NH 64
#define NW 64
#define NHW 4096
#define NTOT ((size_t)NB * NC * NHW)   // 67,108,864 elems

typedef float f32x4 __attribute__((ext_vector_type(4)));
typedef unsigned short u16x4 __attribute__((ext_vector_type(4)));
typedef unsigned int u32x4 __attribute__((ext_vector_type(4)));

// workspace float offsets (every region fully rewritten each launch)
#define OFF_S1PART 0              // [B][C][4jc]        = 65536
#define OFF_F2PART 65536          // [8cg][B][4096pix]  = 1048576
#define OFF_F1SIG  1114112        // [B][C]             = 16384
#define OFF_F2RAW  1130496        // [B][4096]          = 131072
#define OFF_BNPART 1261568        // [512 blocks][2]    = 1024
#define OFF_XBF    1263616        // bf16 copy of x: NTOT ushorts = 134 MB
#define WS_NEED_BYTES ((size_t)OFF_XBF * 4 + NTOT * 2)

// f32 -> bf16 round-to-nearest-even
static __device__ inline unsigned short bf_rne(float f) {
  const unsigned int u = __float_as_uint(f);
  return (unsigned short)((u + 0x7fffu + ((u >> 16) & 1u)) >> 16);
}

// ---------------------------------------------------------------------------
// Kernel A: single pass over x, atomic-free.
//   s1part[b,c,jc]   = sum over the jc-th 1024-pixel chunk of x[b,c,:]
//   f2part[cg,b,pix] = sum over the cg-th 64-channel group of x[b,:,pix]
//   xbf              = bf16(x) (RNE) — 134 MB, intended to stay L3-resident;
//                      x itself is nt-loaded so it does not pollute L3.
// grid = 32 b * 8 cg * 4 jc = 1024 blocks, 256 thr.
__global__ __launch_bounds__(256) void k_reduce(const float* __restrict__ x,
                                                unsigned short* __restrict__ xbf,
                                                float* __restrict__ s1part,
                                                float* __restrict__ f2part) {
  __shared__ f32x4 comb[4][256];
  const int bid = blockIdx.x;
  const int jc = bid & 3;
  const int cg = (bid >> 2) & 7;
  const int b = bid >> 5;
  const int tid = threadIdx.x;
  const int lane = tid & 63;
  const int wv = tid >> 6;

  const size_t base =
      ((size_t)(b * NC + cg * 64 + wv * 16)) * NHW + jc * 1024 + lane * 4;
  f32x4 p0 = {0.f, 0.f, 0.f, 0.f}, p1 = p0, p2 = p0, p3 = p0;
  float myS = 0.f;
#pragma unroll
  for (int k = 0; k < 16; ++k) {
    const size_t idx = base + (size_t)k * NHW;
    const float* xc = x + idx;
    const f32x4 v0 =
        __builtin_nontemporal_load(reinterpret_cast<const f32x4*>(xc + 0));
    const f32x4 v1 =
        __builtin_nontemporal_load(reinterpret_cast<const f32x4*>(xc + 256));
    const f32x4 v2 =
        __builtin_nontemporal_load(reinterpret_cast<const f32x4*>(xc + 512));
    const f32x4 v3 =
        __builtin_nontemporal_load(reinterpret_cast<const f32x4*>(xc + 768));
    p0 += v0; p1 += v1; p2 += v2; p3 += v3;
    const f32x4 t = (v0 + v1) + (v2 + v3);
    float s = (t.x + t.y) + (t.z + t.w);
#pragma unroll
    for (int m = 32; m > 0; m >>= 1) s += __shfl_xor(s, m);
    myS = (lane == k) ? s : myS;  // butterfly leaves total in all lanes
    if (xbf) {                    // wave-uniform branch
      u16x4 h0, h1, h2, h3;
      h0.x = bf_rne(v0.x); h0.y = bf_rne(v0.y); h0.z = bf_rne(v0.z); h0.w = bf_rne(v0.w);
      h1.x = bf_rne(v1.x); h1.y = bf_rne(v1.y); h1.z = bf_rne(v1.z); h1.w = bf_rne(v1.w);
      h2.x = bf_rne(v2.x); h2.y = bf_rne(v2.y); h2.z = bf_rne(v2.z); h2.w = bf_rne(v2.w);
      h3.x = bf_rne(v3.x); h3.y = bf_rne(v3.y); h3.z = bf_rne(v3.z); h3.w = bf_rne(v3.w);
      *reinterpret_cast<u16x4*>(xbf + idx + 0) = h0;
      *reinterpret_cast<u16x4*>(xbf + idx + 256) = h1;
      *reinterpret_cast<u16x4*>(xbf + idx + 512) = h2;
      *reinterpret_cast<u16x4*>(xbf + idx + 768) = h3;
    }
  }
  if (lane < 16)
    s1part[(b * NC + cg * 64 + wv * 16 + lane) * 4 + jc] = myS;

  comb[wv][0 * 64 + lane] = p0;
  comb[wv][1 * 64 + lane] = p1;
  comb[wv][2 * 64 + lane] = p2;
  comb[wv][3 * 64 + lane] = p3;
  __syncthreads();
  const f32x4 r =
      (comb[0][tid] + comb[1][tid]) + (comb[2][tid] + comb[3][tid]);
  reinterpret_cast<f32x4*>(f2part)[((size_t)cg * NB + b) * 1024 + jc * 256 +
                                   tid] = r;
}

// ---------------------------------------------------------------------------
// Kernel B: spatial attention map + f1sig, fused. (unchanged from R6)
__global__ __launch_bounds__(256) void k_f2(const float* __restrict__ f2part,
                                            const float* __restrict__ s1part,
                                            const float* __restrict__ w1,
                                            const float* __restrict__ wh,
                                            const float* __restrict__ ww,
                                            float* __restrict__ f2raw,
                                            float* __restrict__ bnpart,
                                            float* __restrict__ f1sig) {
  __shared__ float mp[66][66];
  __shared__ float wwL[64][193];
  __shared__ float red[8];
  const int b = blockIdx.x >> 4;
  const int rg = blockIdx.x & 15;
  const int tid = threadIdx.x;

  if (tid < 66) {
    mp[0][tid] = 0.f;
    mp[65][tid] = 0.f;
    mp[tid][0] = 0.f;
    mp[tid][65] = 0.f;
  }
  for (int t = tid; t < 64 * 192; t += 256) wwL[t / 192][t % 192] = ww[t];
  for (int t = tid; t < NHW; t += 256) {
    float s = 0.f;
#pragma unroll
    for (int cg = 0; cg < 8; ++cg)
      s += f2part[((size_t)(cg * NB + b)) * NHW + t];
    mp[1 + (t >> 6)][1 + (t & 63)] = s * (1.0f / (float)NC);
  }
  __syncthreads();

  const int i = rg * 4 + (tid >> 6);
  const int j = tid & 63;
  const float* whp = wh + 192 * __builtin_amdgcn_readfirstlane(i);
  const float* wwp = &wwL[j][0];
  float acc = 0.f;
#pragma unroll 16
  for (int ic = 0; ic < 64; ++ic) {
    acc += whp[ic * 3 + 0] * mp[ic + 1][j] +
           whp[ic * 3 + 1] * mp[ic + 1][j + 1] +
           whp[ic * 3 + 2] * mp[ic + 1][j + 2];
    acc += wwp[ic * 3 + 0] * mp[i][ic + 1] +
           wwp[ic * 3 + 1] * mp[i + 1][ic + 1] +
           wwp[ic * 3 + 2] * mp[i + 2][ic + 1];
  }
  f2raw[(size_t)b * NHW + (i << 6) + j] = acc;

  float lsum = acc, lsq = acc * acc;
#pragma unroll
  for (int off = 32; off > 0; off >>= 1) {
    lsum += __shfl_down(lsum, off);
    lsq += __shfl_down(lsq, off);
  }
  if ((tid & 63) == 0) {
    red[(tid >> 6) * 2 + 0] = lsum;
    red[(tid >> 6) * 2 + 1] = lsq;
  }
  __syncthreads();
  if (tid == 0) {
    bnpart[blockIdx.x * 2 + 0] = red[0] + red[2] + red[4] + red[6];
    bnpart[blockIdx.x * 2 + 1] = red[1] + red[3] + red[5] + red[7];
  }

  if (rg == 0) {
#pragma unroll
    for (int c0 = 0; c0 < 512; c0 += 256) {
      const int c = c0 + tid;
      float acc5 = 0.f;
#pragma unroll
      for (int k = 0; k < 5; ++k) {
        const int cc = c + k - 2;
        if (cc >= 0 && cc < NC) {
          const f32x4 sp = reinterpret_cast<const f32x4*>(s1part)[b * NC + cc];
          acc5 += w1[k] * ((sp.x + sp.y) + (sp.z + sp.w));
        }
      }
      acc5 *= (1.0f / (float)NHW);
      f1sig[b * NC + c] = 1.0f / (1.0f + __expf(-acc5));
    }
  }
}

// ---------------------------------------------------------------------------
// Kernel C (bf16 path): out = bf16(x) * f1 * sigmoid(g*(f2-mu)+bt).
// xbf (134 MB) should be L3-resident from k_reduce. 8 elems/thread/b.
__global__ __launch_bounds__(256) void k_out_bf(
    const unsigned short* __restrict__ xbf, const float* __restrict__ f1sig,
    const float* __restrict__ f2raw, const float* __restrict__ bnpart,
    const float* __restrict__ gamma, const float* __restrict__ beta,
    float* __restrict__ out) {
  __shared__ float bnv[2];
  const int tid = threadIdx.x;
  if (tid < 64) {
    float s = 0.f, q = 0.f;
#pragma unroll
    for (int r = 0; r < 8; ++r) {
      s += bnpart[2 * (tid + 64 * r) + 0];
      q += bnpart[2 * (tid + 64 * r) + 1];
    }
#pragma unroll
    for (int off = 32; off > 0; off >>= 1) {
      s += __shfl_down(s, off);
      q += __shfl_down(q, off);
    }
    if (tid == 0) {
      const float N = (float)(NB * NHW);
      const float mu = s / N;
      const float var = q / N - mu * mu;
      bnv[0] = mu;
      bnv[1] = gamma[0] * rsqrtf(var + 1e-5f);
    }
  }
  __syncthreads();
  const float mu = bnv[0];
  const float g = bnv[1];
  const float bt = beta[0];

  const int gid = blockIdx.x * 256 + tid;  // 0..262143
  const int e0 = gid * 8;                  // elem within one b-plane (2M)
  const int c = e0 >> 12;
  const int hw = e0 & 4095;

  for (int b = 0; b < NB; ++b) {
    const size_t plane = (size_t)b * (NC * NHW);
    const u32x4 hv =
        *reinterpret_cast<const u32x4*>(xbf + plane + e0);  // 8 bf16
    const f32x4 f2a =
        *reinterpret_cast<const f32x4*>(f2raw + b * NHW + hw);
    const f32x4 f2b =
        *reinterpret_cast<const f32x4*>(f2raw + b * NHW + hw + 4);
    const float f1 = f1sig[b * NC + c];
    f32x4 oa, ob;
    {
      const float x0 = __uint_as_float(hv.x << 16);
      const float x1 = __uint_as_float(hv.x & 0xffff0000u);
      const float x2 = __uint_as_float(hv.y << 16);
      const float x3 = __uint_as_float(hv.y & 0xffff0000u);
      const float x4 = __uint_as_float(hv.z << 16);
      const float x5 = __uint_as_float(hv.z & 0xffff0000u);
      const float x6 = __uint_as_float(hv.w << 16);
      const float x7 = __uint_as_float(hv.w & 0xffff0000u);
      oa.x = x0 * f1 * (1.0f / (1.0f + __expf(-(g * (f2a.x - mu) + bt))));
      oa.y = x1 * f1 * (1.0f / (1.0f + __expf(-(g * (f2a.y - mu) + bt))));
      oa.z = x2 * f1 * (1.0f / (1.0f + __expf(-(g * (f2a.z - mu) + bt))));
      oa.w = x3 * f1 * (1.0f / (1.0f + __expf(-(g * (f2a.w - mu) + bt))));
      ob.x = x4 * f1 * (1.0f / (1.0f + __expf(-(g * (f2b.x - mu) + bt))));
      ob.y = x5 * f1 * (1.0f / (1.0f + __expf(-(g * (f2b.y - mu) + bt))));
      ob.z = x6 * f1 * (1.0f / (1.0f + __expf(-(g * (f2b.z - mu) + bt))));
      ob.w = x7 * f1 * (1.0f / (1.0f + __expf(-(g * (f2b.w - mu) + bt))));
    }
    f32x4* op = reinterpret_cast<f32x4*>(out + plane + e0);
    __builtin_nontemporal_store(oa, op + 0);
    __builtin_nontemporal_store(ob, op + 1);
  }
}

// ---------------------------------------------------------------------------
// Kernel C (fallback, f32 path — R6 behavior, reverse traversal).
__global__ __launch_bounds__(256) void k_out_f32(
    const float* __restrict__ x, const float* __restrict__ f1sig,
    const float* __restrict__ f2raw, const float* __restrict__ bnpart,
    const float* __restrict__ gamma, const float* __restrict__ beta,
    float* __restrict__ out) {
  __shared__ float bnv[2];
  const int tid = threadIdx.x;
  if (tid < 64) {
    float s = 0.f, q = 0.f;
#pragma unroll
    for (int r = 0; r < 8; ++r) {
      s += bnpart[2 * (tid + 64 * r) + 0];
      q += bnpart[2 * (tid + 64 * r) + 1];
    }
#pragma unroll
    for (int off = 32; off > 0; off >>= 1) {
      s += __shfl_down(s, off);
      q += __shfl_down(q, off);
    }
    if (tid == 0) {
      const float N = (float)(NB * NHW);
      const float mu = s / N;
      const float var = q / N - mu * mu;
      bnv[0] = mu;
      bnv[1] = gamma[0] * rsqrtf(var + 1e-5f);
    }
  }
  __syncthreads();
  const float mu = bnv[0];
  const float g = bnv[1];
  const float bt = beta[0];

  const int bid = gridDim.x - 1 - blockIdx.x;
  const int gid = bid * 256 + tid;
  const int hw4 = gid & 1023;
  const int cq = gid >> 10;
  const f32x4* xp = reinterpret_cast<const f32x4*>(x) + gid;
  const f32x4* fp = reinterpret_cast<const f32x4*>(f2raw) + hw4;
  const float* f1p = f1sig + cq;
  f32x4* op = reinterpret_cast<f32x4*>(out) + gid;

  for (int b = NB - 1; b >= 0; --b) {
    const f32x4 xv = xp[(size_t)b * 524288];
    const f32x4 fv = fp[(size_t)b * 1024];
    const float f1 = f1p[(size_t)b * 512];
    f32x4 ov;
    ov.x = xv.x * f1 * (1.0f / (1.0f + __expf(-(g * (fv.x - mu) + bt))));
    ov.y = xv.y * f1 * (1.0f / (1.0f + __expf(-(g * (fv.y - mu) + bt))));
    ov.z = xv.z * f1 * (1.0f / (1.0f + __expf(-(g * (fv.z - mu) + bt))));
    ov.w = xv.w * f1 * (1.0f / (1.0f + __expf(-(g * (fv.w - mu) + bt))));
    __builtin_nontemporal_store(ov, op + (size_t)b * 524288);
  }
}

// ---------------------------------------------------------------------------
extern "C" void kernel_launch(void* const* d_in, const int* in_sizes, int n_in,
                              void* d_out, int out_size, void* d_ws,
                              size_t ws_size, hipStream_t stream) {
  const float* x = (const float*)d_in[0];
  const float* w1 = (const float*)d_in[1];
  const float* wh = (const float*)d_in[2];
  const float* ww = (const float*)d_in[3];
  const float* gamma = (const float*)d_in[4];
  const float* beta = (const float*)d_in[5];
  float* out = (float*)d_out;
  float* ws = (float*)d_ws;

  float* s1part = ws + OFF_S1PART;
  float* f2part = ws + OFF_F2PART;
  float* f1sig = ws + OFF_F1SIG;
  float* f2raw = ws + OFF_F2RAW;
  float* bnpart = ws + OFF_BNPART;
  const bool big = ws_size >= WS_NEED_BYTES;
  unsigned short* xbf = big ? (unsigned short*)(ws + OFF_XBF) : nullptr;

  k_reduce<<<NB * 8 * 4, 256, 0, stream>>>(x, xbf, s1part, f2part);
  k_f2<<<NB * 16, 256, 0, stream>>>(f2part, s1part, w1, wh, ww, f2raw, bnpart,
                                    f1sig);
  if (big) {
    k_out_bf<<<1024, 256, 0, stream>>>(xbf, f1sig, f2raw, bnpart, gamma, beta,
                                       out);
  } else {
    k_out_f32<<<2048, 256, 0, stream>>>(x, f1sig, f2raw, bnpart, gamma, beta,
                                        out);
  }
}

// Round 8
// 159.141 us; speedup vs baseline: 1.3626x; 1.3626x over previous
//
#include <hip/hip_runtime.h>

// x [B=32, C=512, H=64, W=64] fp32
#define NB 32
#define NC 512
#define NH 64
#define NW 64
#define NHW 4096
#define NTOT ((size_t)NB * NC * NHW)

typedef float f32x4 __attribute__((ext_vector_type(4)));

// workspace float offsets (every region fully rewritten each launch)
#define OFF_S1PART 0              // [B][C][16jc]       = 262144
#define OFF_F2PART 262144         // [8cg][B][4096pix]  = 1048576
#define OFF_F1SIG  1310720        // [B][C]             = 16384
#define OFF_F2RAW  1327104        // [B][4096]          = 131072
#define OFF_BNPART 1458176        // [512 blocks][2]    = 1024

// ---------------------------------------------------------------------------
// Kernel A: ordered-sweep reduction pass over x, atomic-free.
//   s1part[b,c,jc]   = sum over the jc-th 256-pixel chunk of x[b,c,:]
//   f2part[cg,b,pix] = sum over the cg-th 64-channel group of x[b,:,pix]
// grid = 4096 blocks: bid = b*128 + cg*16 + jc  (b in HIGH bits!). With ~2048
// resident, dispatch drains b ascending -> at kernel end the MALL holds a
// CONTIGUOUS high-b tail of x (~240 MB), which k_out's reverse sweep consumes
// as L3 hits. Each block: 64 channels x 256 pixels = 64 KB of x.
// Wave w owns channels cg*64+w*16..+15: one float4/lane per channel (1 KB
// coalesced), per-channel 6-step butterfly for s1 (myS captured at lane==k).
__global__ __launch_bounds__(256) void k_reduce(const float* __restrict__ x,
                                                float* __restrict__ s1part,
                                                float* __restrict__ f2part) {
  __shared__ f32x4 comb[4][64];
  const int bid = blockIdx.x;
  const int jc = bid & 15;
  const int cg = (bid >> 4) & 7;
  const int b = bid >> 7;
  const int tid = threadIdx.x;
  const int lane = tid & 63;
  const int wv = tid >> 6;

  const size_t base =
      ((size_t)(b * NC + cg * 64 + wv * 16)) * NHW + jc * 256 + lane * 4;
  f32x4 p = {0.f, 0.f, 0.f, 0.f};
  float myS = 0.f;
#pragma unroll
  for (int k = 0; k < 16; ++k) {
    const f32x4 v = *reinterpret_cast<const f32x4*>(x + base + (size_t)k * NHW);
    p += v;
    float s = (v.x + v.y) + (v.z + v.w);
#pragma unroll
    for (int m = 32; m > 0; m >>= 1) s += __shfl_xor(s, m);
    myS = (lane == k) ? s : myS;  // butterfly leaves total in all lanes
  }
  if (lane < 16)
    s1part[(size_t)(b * NC + cg * 64 + wv * 16 + lane) * 16 + jc] = myS;

  comb[wv][lane] = p;
  __syncthreads();
  if (tid < 64) {
    const f32x4 r =
        (comb[0][tid] + comb[1][tid]) + (comb[2][tid] + comb[3][tid]);
    reinterpret_cast<f32x4*>(f2part)[((size_t)cg * NB + b) * 1024 + jc * 64 +
                                     tid] = r;
  }
}

// ---------------------------------------------------------------------------
// Kernel B: spatial attention map + f1sig, fused.
//   m[r,c] = (1/512) * sum_cg f2part[cg,b,r*64+c]        (built in LDS, halo)
//   f2raw[b,i,j] = sum_{ic,k} m[ic,j+k-1]*wh[i,ic,k] + m[i+k-1,ic]*ww[j,ic,k]
//   bnpart[blk] = (sum, sumsq) over this block's 256 outputs
//   rg==0 blocks additionally: f1sig[b,c] = sigmoid(conv5(s1sum)/4096)
// grid = 32 b * 16 rowgroups(4 rows) = 512 blocks, 256 thr, 1 output/thread.
// Staging now float4 (32 global loads/thread instead of 128).
__global__ __launch_bounds__(256) void k_f2(const float* __restrict__ f2part,
                                            const float* __restrict__ s1part,
                                            const float* __restrict__ w1,
                                            const float* __restrict__ wh,
                                            const float* __restrict__ ww,
                                            float* __restrict__ f2raw,
                                            float* __restrict__ bnpart,
                                            float* __restrict__ f1sig) {
  __shared__ float mp[66][66];
  __shared__ float wwL[64][193];
  __shared__ float red[8];
  const int b = blockIdx.x >> 4;
  const int rg = blockIdx.x & 15;
  const int tid = threadIdx.x;

  if (tid < 66) {
    mp[0][tid] = 0.f;
    mp[65][tid] = 0.f;
    mp[tid][0] = 0.f;
    mp[tid][65] = 0.f;
  }
  for (int t = tid; t < 64 * 192; t += 256) wwL[t / 192][t % 192] = ww[t];
  // build channel-mean map with halo offset, float4-vectorized
#pragma unroll
  for (int t4 = tid; t4 < 1024; t4 += 256) {
    f32x4 s = {0.f, 0.f, 0.f, 0.f};
#pragma unroll
    for (int cg = 0; cg < 8; ++cg)
      s += reinterpret_cast<const f32x4*>(f2part +
                                          ((size_t)(cg * NB + b)) * NHW)[t4];
    s *= (1.0f / (float)NC);
    const int r = t4 >> 4;
    const int c = (t4 & 15) * 4;
    mp[1 + r][1 + c + 0] = s.x;
    mp[1 + r][1 + c + 1] = s.y;
    mp[1 + r][1 + c + 2] = s.z;
    mp[1 + r][1 + c + 3] = s.w;
  }
  __syncthreads();

  const int i = rg * 4 + (tid >> 6);  // wave-uniform row
  const int j = tid & 63;             // lane = output column
  const float* whp = wh + 192 * __builtin_amdgcn_readfirstlane(i);
  const float* wwp = &wwL[j][0];
  float acc = 0.f;
#pragma unroll 16
  for (int ic = 0; ic < 64; ++ic) {
    acc += whp[ic * 3 + 0] * mp[ic + 1][j] +
           whp[ic * 3 + 1] * mp[ic + 1][j + 1] +
           whp[ic * 3 + 2] * mp[ic + 1][j + 2];
    acc += wwp[ic * 3 + 0] * mp[i][ic + 1] +
           wwp[ic * 3 + 1] * mp[i + 1][ic + 1] +
           wwp[ic * 3 + 2] * mp[i + 2][ic + 1];
  }
  f2raw[(size_t)b * NHW + (i << 6) + j] = acc;

  float lsum = acc, lsq = acc * acc;
#pragma unroll
  for (int off = 32; off > 0; off >>= 1) {
    lsum += __shfl_down(lsum, off);
    lsq += __shfl_down(lsq, off);
  }
  if ((tid & 63) == 0) {
    red[(tid >> 6) * 2 + 0] = lsum;
    red[(tid >> 6) * 2 + 1] = lsq;
  }
  __syncthreads();
  if (tid == 0) {
    bnpart[blockIdx.x * 2 + 0] = red[0] + red[2] + red[4] + red[6];
    bnpart[blockIdx.x * 2 + 1] = red[1] + red[3] + red[5] + red[7];
  }

  if (rg == 0) {
#pragma unroll
    for (int c0 = 0; c0 < 512; c0 += 256) {
      const int c = c0 + tid;
      float acc5 = 0.f;
#pragma unroll
      for (int k = 0; k < 5; ++k) {
        const int cc = c + k - 2;
        if (cc >= 0 && cc < NC) {
          const f32x4* sp =
              reinterpret_cast<const f32x4*>(s1part + (size_t)(b * NC + cc) * 16);
          const f32x4 a = (sp[0] + sp[1]) + (sp[2] + sp[3]);
          acc5 += w1[k] * ((a.x + a.y) + (a.z + a.w));
        }
      }
      acc5 *= (1.0f / (float)NHW);
      f1sig[b * NC + c] = 1.0f / (1.0f + __expf(-acc5));
    }
  }
}

// ---------------------------------------------------------------------------
// Kernel C: out = x * f1sig[b,c] * sigmoid(g*(f2-mu)+beta).
// BN finalize inline by wave 0 of every block. Coordinated REVERSE sweep
// (descending b, reversed block mapping): consumes k_reduce's contiguous
// high-b L3 tail first; nt-stores keep `out` from evicting x; ends at b=0,
// priming the next replay's ascending k_reduce.
__global__ __launch_bounds__(256) void k_out(const float* __restrict__ x,
                                             const float* __restrict__ f1sig,
                                             const float* __restrict__ f2raw,
                                             const float* __restrict__ bnpart,
                                             const float* __restrict__ gamma,
                                             const float* __restrict__ beta,
                                             float* __restrict__ out) {
  __shared__ float bnv[2];
  const int tid = threadIdx.x;
  if (tid < 64) {
    float s = 0.f, q = 0.f;
#pragma unroll
    for (int r = 0; r < 8; ++r) {
      s += bnpart[2 * (tid + 64 * r) + 0];
      q += bnpart[2 * (tid + 64 * r) + 1];
    }
#pragma unroll
    for (int off = 32; off > 0; off >>= 1) {
      s += __shfl_down(s, off);
      q += __shfl_down(q, off);
    }
    if (tid == 0) {
      const float N = (float)(NB * NHW);
      const float mu = s / N;
      const float var = q / N - mu * mu;
      bnv[0] = mu;
      bnv[1] = gamma[0] * rsqrtf(var + 1e-5f);
    }
  }
  __syncthreads();
  const float mu = bnv[0];
  const float g = bnv[1];
  const float bt = beta[0];

  const int bid = gridDim.x - 1 - blockIdx.x;  // reversed block mapping
  const int gid = bid * 256 + tid;             // 0..524287
  const int hw4 = gid & 1023;
  const int cq = gid >> 10;
  const f32x4* xp = reinterpret_cast<const f32x4*>(x) + gid;
  const f32x4* fp = reinterpret_cast<const f32x4*>(f2raw) + hw4;
  const float* f1p = f1sig + cq;
  f32x4* op = reinterpret_cast<f32x4*>(out) + gid;

  for (int b = NB - 1; b >= 0; --b) {
    const f32x4 xv = xp[(size_t)b * 524288];
    const f32x4 fv = fp[(size_t)b * 1024];
    const float f1 = f1p[(size_t)b * 512];
    f32x4 ov;
    ov.x = xv.x * f1 * (1.0f / (1.0f + __expf(-(g * (fv.x - mu) + bt))));
    ov.y = xv.y * f1 * (1.0f / (1.0f + __expf(-(g * (fv.y - mu) + bt))));
    ov.z = xv.z * f1 * (1.0f / (1.0f + __expf(-(g * (fv.z - mu) + bt))));
    ov.w = xv.w * f1 * (1.0f / (1.0f + __expf(-(g * (fv.w - mu) + bt))));
    __builtin_nontemporal_store(ov, op + (size_t)b * 524288);
  }
}

// ---------------------------------------------------------------------------
extern "C" void kernel_launch(void* const* d_in, const int* in_sizes, int n_in,
                              void* d_out, int out_size, void* d_ws,
                              size_t ws_size, hipStream_t stream) {
  const float* x = (const float*)d_in[0];
  const float* w1 = (const float*)d_in[1];
  const float* wh = (const float*)d_in[2];
  const float* ww = (const float*)d_in[3];
  const float* gamma = (const float*)d_in[4];
  const float* beta = (const float*)d_in[5];
  float* out = (float*)d_out;
  float* ws = (float*)d_ws;

  float* s1part = ws + OFF_S1PART;
  float* f2part = ws + OFF_F2PART;
  float* f1sig = ws + OFF_F1SIG;
  float* f2raw = ws + OFF_F2RAW;
  float* bnpart = ws + OFF_BNPART;

  k_reduce<<<NB * 8 * 16, 256, 0, stream>>>(x, s1part, f2part);
  k_f2<<<NB * 16, 256, 0, stream>>>(f2part, s1part, w1, wh, ww, f2raw, bnpart,
                                    f1sig);
  k_out<<<2048, 256, 0, stream>>>(x, f1sig, f2raw, bnpart, gamma, beta, out);
}

// Round 9
// 146.771 us; speedup vs baseline: 1.4775x; 1.0843x over previous
//
#include <hip/hip_runtime.h>

// x [B=32, C=512, H=64, W=64] fp32
#define NB 32
#define NC 512
#define NH 64
#define NW 64
#define NHW 4096
#define NTOT ((size_t)NB * NC * NHW)

typedef float f32x4 __attribute__((ext_vector_type(4)));

// workspace float offsets (every region fully rewritten each launch)
#define OFF_S1PART 0              // [B][C][16jc]       = 262144
#define OFF_F2PART 262144         // [8cg][B][4096pix]  = 1048576
#define OFF_F1SIG  1310720        // [B][C]             = 16384
#define OFF_F2RAW  1327104        // [B][4096]          = 131072
#define OFF_BNPART 1458176        // [512 blocks][2]    = 1024

// ---------------------------------------------------------------------------
// Kernel A: ordered-sweep reduction pass over x, atomic-free.
//   s1part[b,c,jc]   = sum over the jc-th 256-pixel chunk of x[b,c,:]
//   f2part[cg,b,pix] = sum over the cg-th 64-channel group of x[b,:,pix]
// grid = 4096 blocks: bid = b*128 + cg*16 + jc (b in high bits -> ascending
// drain). Block = 64 channels x 256 pixels = 64 KB of x. Wave wv owns
// channels cg*64+wv*16..+15; lane l -> pixels jc*256+l*4..+3.
__global__ __launch_bounds__(256) void k_reduce(const float* __restrict__ x,
                                                float* __restrict__ s1part,
                                                float* __restrict__ f2part) {
  __shared__ f32x4 comb[4][64];
  const int bid = blockIdx.x;
  const int jc = bid & 15;
  const int cg = (bid >> 4) & 7;
  const int b = bid >> 7;
  const int tid = threadIdx.x;
  const int lane = tid & 63;
  const int wv = tid >> 6;

  const size_t base =
      ((size_t)(b * NC + cg * 64 + wv * 16)) * NHW + jc * 256 + lane * 4;
  f32x4 p = {0.f, 0.f, 0.f, 0.f};
  float myS = 0.f;
#pragma unroll
  for (int k = 0; k < 16; ++k) {
    const f32x4 v = *reinterpret_cast<const f32x4*>(x + base + (size_t)k * NHW);
    p += v;
    float s = (v.x + v.y) + (v.z + v.w);
#pragma unroll
    for (int m = 32; m > 0; m >>= 1) s += __shfl_xor(s, m);
    myS = (lane == k) ? s : myS;  // butterfly leaves total in all lanes
  }
  if (lane < 16)
    s1part[(size_t)(b * NC + cg * 64 + wv * 16 + lane) * 16 + jc] = myS;

  comb[wv][lane] = p;
  __syncthreads();
  if (tid < 64) {
    const f32x4 r =
        (comb[0][tid] + comb[1][tid]) + (comb[2][tid] + comb[3][tid]);
    reinterpret_cast<f32x4*>(f2part)[((size_t)cg * NB + b) * 1024 + jc * 64 +
                                     tid] = r;
  }
}

// ---------------------------------------------------------------------------
// Kernel B: spatial attention map + f1sig, fused. (unchanged, ~12 us)
__global__ __launch_bounds__(256) void k_f2(const float* __restrict__ f2part,
                                            const float* __restrict__ s1part,
                                            const float* __restrict__ w1,
                                            const float* __restrict__ wh,
                                            const float* __restrict__ ww,
                                            float* __restrict__ f2raw,
                                            float* __restrict__ bnpart,
                                            float* __restrict__ f1sig) {
  __shared__ float mp[66][66];
  __shared__ float wwL[64][193];
  __shared__ float red[8];
  const int b = blockIdx.x >> 4;
  const int rg = blockIdx.x & 15;
  const int tid = threadIdx.x;

  if (tid < 66) {
    mp[0][tid] = 0.f;
    mp[65][tid] = 0.f;
    mp[tid][0] = 0.f;
    mp[tid][65] = 0.f;
  }
  for (int t = tid; t < 64 * 192; t += 256) wwL[t / 192][t % 192] = ww[t];
#pragma unroll
  for (int t4 = tid; t4 < 1024; t4 += 256) {
    f32x4 s = {0.f, 0.f, 0.f, 0.f};
#pragma unroll
    for (int cg = 0; cg < 8; ++cg)
      s += reinterpret_cast<const f32x4*>(f2part +
                                          ((size_t)(cg * NB + b)) * NHW)[t4];
    s *= (1.0f / (float)NC);
    const int r = t4 >> 4;
    const int c = (t4 & 15) * 4;
    mp[1 + r][1 + c + 0] = s.x;
    mp[1 + r][1 + c + 1] = s.y;
    mp[1 + r][1 + c + 2] = s.z;
    mp[1 + r][1 + c + 3] = s.w;
  }
  __syncthreads();

  const int i = rg * 4 + (tid >> 6);  // wave-uniform row
  const int j = tid & 63;             // lane = output column
  const float* whp = wh + 192 * __builtin_amdgcn_readfirstlane(i);
  const float* wwp = &wwL[j][0];
  float acc = 0.f;
#pragma unroll 16
  for (int ic = 0; ic < 64; ++ic) {
    acc += whp[ic * 3 + 0] * mp[ic + 1][j] +
           whp[ic * 3 + 1] * mp[ic + 1][j + 1] +
           whp[ic * 3 + 2] * mp[ic + 1][j + 2];
    acc += wwp[ic * 3 + 0] * mp[i][ic + 1] +
           wwp[ic * 3 + 1] * mp[i + 1][ic + 1] +
           wwp[ic * 3 + 2] * mp[i + 2][ic + 1];
  }
  f2raw[(size_t)b * NHW + (i << 6) + j] = acc;

  float lsum = acc, lsq = acc * acc;
#pragma unroll
  for (int off = 32; off > 0; off >>= 1) {
    lsum += __shfl_down(lsum, off);
    lsq += __shfl_down(lsq, off);
  }
  if ((tid & 63) == 0) {
    red[(tid >> 6) * 2 + 0] = lsum;
    red[(tid >> 6) * 2 + 1] = lsq;
  }
  __syncthreads();
  if (tid == 0) {
    bnpart[blockIdx.x * 2 + 0] = red[0] + red[2] + red[4] + red[6];
    bnpart[blockIdx.x * 2 + 1] = red[1] + red[3] + red[5] + red[7];
  }

  if (rg == 0) {
#pragma unroll
    for (int c0 = 0; c0 < 512; c0 += 256) {
      const int c = c0 + tid;
      float acc5 = 0.f;
#pragma unroll
      for (int k = 0; k < 5; ++k) {
        const int cc = c + k - 2;
        if (cc >= 0 && cc < NC) {
          const f32x4* sp =
              reinterpret_cast<const f32x4*>(s1part + (size_t)(b * NC + cc) * 16);
          const f32x4 a = (sp[0] + sp[1]) + (sp[2] + sp[3]);
          acc5 += w1[k] * ((a.x + a.y) + (a.z + a.w));
        }
      }
      acc5 *= (1.0f / (float)NHW);
      f1sig[b * NC + c] = 1.0f / (1.0f + __expf(-acc5));
    }
  }
}

// ---------------------------------------------------------------------------
// Kernel C: out = x * f1sig[b,c] * sig2[b,hw], region-mirrored to k_reduce.
// Block bid covers the SAME 64ch x 256px region as k_reduce block bid (same
// XCD under round-robin placement -> L2 reuse), dispatched in reverse groups
// of 8 (preserves bid%8, consumes k_reduce's L3 tail first).
// Per thread: ONE f2raw float4 -> 4 sigmoids total (reused across all 16
// channels), 16 wave-uniform f1 scalars (s_load), 16 x-loads + 16 nt-stores.
__global__ __launch_bounds__(256) void k_out(const float* __restrict__ x,
                                             const float* __restrict__ f1sig,
                                             const float* __restrict__ f2raw,
                                             const float* __restrict__ bnpart,
                                             const float* __restrict__ gamma,
                                             const float* __restrict__ beta,
                                             float* __restrict__ out) {
  __shared__ float bnv[2];
  const int tid = threadIdx.x;
  if (tid < 64) {
    float s = 0.f, q = 0.f;
#pragma unroll
    for (int r = 0; r < 8; ++r) {
      s += bnpart[2 * (tid + 64 * r) + 0];
      q += bnpart[2 * (tid + 64 * r) + 1];
    }
#pragma unroll
    for (int off = 32; off > 0; off >>= 1) {
      s += __shfl_down(s, off);
      q += __shfl_down(q, off);
    }
    if (tid == 0) {
      const float N = (float)(NB * NHW);
      const float mu = s / N;
      const float var = q / N - mu * mu;
      bnv[0] = mu;
      bnv[1] = gamma[0] * rsqrtf(var + 1e-5f);
    }
  }
  __syncthreads();
  const float mu = bnv[0];
  const float g = bnv[1];
  const float bt = beta[0];

  // reverse dispatch in groups of 8: same bid%8 (XCD), descending globally
  const int grp = blockIdx.x >> 3;
  const int bid = (511 - grp) * 8 + (blockIdx.x & 7);
  const int jc = bid & 15;
  const int cg = (bid >> 4) & 7;
  const int b = bid >> 7;
  const int lane = tid & 63;
  const int wv = tid >> 6;

  const int px = jc * 256 + lane * 4;
  const f32x4 fv = *reinterpret_cast<const f32x4*>(f2raw + b * NHW + px);
  f32x4 s2;
  s2.x = 1.0f / (1.0f + __expf(-(g * (fv.x - mu) + bt)));
  s2.y = 1.0f / (1.0f + __expf(-(g * (fv.y - mu) + bt)));
  s2.z = 1.0f / (1.0f + __expf(-(g * (fv.z - mu) + bt)));
  s2.w = 1.0f / (1.0f + __expf(-(g * (fv.w - mu) + bt)));

  const int cbase = __builtin_amdgcn_readfirstlane(b * NC + cg * 64 + wv * 16);
  float f1v[16];
#pragma unroll
  for (int k = 0; k < 16; ++k) f1v[k] = f1sig[cbase + k];

  const size_t base = (size_t)cbase * NHW + px;
#pragma unroll
  for (int k = 0; k < 16; ++k) {
    const f32x4 xv = *reinterpret_cast<const f32x4*>(x + base + (size_t)k * NHW);
    const f32x4 ov = xv * (s2 * f1v[k]);
    __builtin_nontemporal_store(
        ov, reinterpret_cast<f32x4*>(out + base + (size_t)k * NHW));
  }
}

// ---------------------------------------------------------------------------
extern "C" void kernel_launch(void* const* d_in, const int* in_sizes, int n_in,
                              void* d_out, int out_size, void* d_ws,
                              size_t ws_size, hipStream_t stream) {
  const float* x = (const float*)d_in[0];
  const float* w1 = (const float*)d_in[1];
  const float* wh = (const float*)d_in[2];
  const float* ww = (const float*)d_in[3];
  const float* gamma = (const float*)d_in[4];
  const float* beta = (const float*)d_in[5];
  float* out = (float*)d_out;
  float* ws = (float*)d_ws;

  float* s1part = ws + OFF_S1PART;
  float* f2part = ws + OFF_F2PART;
  float* f1sig = ws + OFF_F1SIG;
  float* f2raw = ws + OFF_F2RAW;
  float* bnpart = ws + OFF_BNPART;

  k_reduce<<<NB * 8 * 16, 256, 0, stream>>>(x, s1part, f2part);
  k_f2<<<NB * 16, 256, 0, stream>>>(f2part, s1part, w1, wh, ww, f2raw, bnpart,
                                    f1sig);
  k_out<<<NB * 8 * 16, 256, 0, stream>>>(x, f1sig, f2raw, bnpart, gamma, beta,
                                         out);
}

// Round 10
// 145.389 us; speedup vs baseline: 1.4915x; 1.0095x over previous
//
#include <hip/hip_runtime.h>

// x [B=32, C=512, H=64, W=64] fp32
#define NB 32
#define NC 512
#define NH 64
#define NW 64
#define NHW 4096
#define NTOT ((size_t)NB * NC * NHW)

typedef float f32x4 __attribute__((ext_vector_type(4)));

// workspace float offsets (every region fully rewritten each launch)
#define OFF_S1PART 0              // [B][C][16jc]       = 262144
#define OFF_F2PART 262144         // [8cg][B][4096pix]  = 1048576
#define OFF_F1SIG  1310720        // [B][C]             = 16384
#define OFF_F2RAW  1327104        // [B][4096]          = 131072
#define OFF_BNPART 1458176        // [256 blocks][2]    = 512

// ---------------------------------------------------------------------------
// Kernel A: ordered-sweep reduction pass over x, atomic-free.
//   s1part[b,c,jc]   = sum over the jc-th 256-pixel chunk of x[b,c,:]
//   f2part[cg,b,pix] = sum over the cg-th 64-channel group of x[b,:,pix]
// grid = 4096 blocks: bid = b*128 + cg*16 + jc (b high bits -> ascending
// drain). Block = 64 ch x 256 px = 64 KB of x.
// Cross-lane s1 reduction via LDS transpose (16 ds_write + 16 ds_read +
// 2 shfl per wave) instead of 96 butterfly shuffles -> ~60% less DS-pipe
// work interleaved with the VMEM stream. sbuf rows padded to 65: transpose
// reads hit 2 lanes/bank (free); writes stride-1 (free).
__global__ __launch_bounds__(256) void k_reduce(const float* __restrict__ x,
                                                float* __restrict__ s1part,
                                                float* __restrict__ f2part) {
  __shared__ float sbuf[4][16][65];
  __shared__ f32x4 comb[4][64];
  const int bid = blockIdx.x;
  const int jc = bid & 15;
  const int cg = (bid >> 4) & 7;
  const int b = bid >> 7;
  const int tid = threadIdx.x;
  const int lane = tid & 63;
  const int wv = tid >> 6;

  const size_t base =
      ((size_t)(b * NC + cg * 64 + wv * 16)) * NHW + jc * 256 + lane * 4;
  f32x4 p = {0.f, 0.f, 0.f, 0.f};
#pragma unroll
  for (int k = 0; k < 16; ++k) {
    const f32x4 v = *reinterpret_cast<const f32x4*>(x + base + (size_t)k * NHW);
    p += v;
    sbuf[wv][k][lane] = (v.x + v.y) + (v.z + v.w);
  }
  comb[wv][lane] = p;
  __syncthreads();

  // s1: 4 lanes per channel, each sums 16 of the 64 per-lane partials
  {
    const int c = lane >> 2;            // channel 0..15 within this wave's set
    const int seg = (lane & 3) * 16;
    float t = 0.f;
#pragma unroll
    for (int m = 0; m < 16; ++m) t += sbuf[wv][c][seg + m];
    t += __shfl_xor(t, 1);
    t += __shfl_xor(t, 2);
    if ((lane & 3) == 0)
      s1part[(size_t)(b * NC + cg * 64 + wv * 16 + c) * 16 + jc] = t;
  }

  if (tid < 64) {
    const f32x4 r =
        (comb[0][tid] + comb[1][tid]) + (comb[2][tid] + comb[3][tid]);
    reinterpret_cast<f32x4*>(f2part)[((size_t)cg * NB + b) * 1024 + jc * 64 +
                                     tid] = r;
  }
}

// ---------------------------------------------------------------------------
// Kernel B: spatial attention map + f1sig, fused. 2 outputs/thread.
// grid = 32 b * 8 rowgroups(8 rows) = 256 blocks (1/CU), 256 thr.
// Wave wv handles rows rg*8 + wv*2 + {0,1}, j = lane. Read amortization:
// h-conv mp reads are row-independent (shared by the pair), w-conv needs 4
// mp rows (vs 6 separate), wwL taps shared -> 10 LDS reads / 2 outputs / ic
// (was 18). wh reads wave-uniform (scalar); mp w-reads broadcast; wwL reads
// 2-way (free).
__global__ __launch_bounds__(256) void k_f2(const float* __restrict__ f2part,
                                            const float* __restrict__ s1part,
                                            const float* __restrict__ w1,
                                            const float* __restrict__ wh,
                                            const float* __restrict__ ww,
                                            float* __restrict__ f2raw,
                                            float* __restrict__ bnpart,
                                            float* __restrict__ f1sig) {
  __shared__ float mp[66][66];
  __shared__ float wwL[64][193];
  __shared__ float red[8];
  const int b = blockIdx.x >> 3;
  const int rg = blockIdx.x & 7;
  const int tid = threadIdx.x;

  if (tid < 66) {
    mp[0][tid] = 0.f;
    mp[65][tid] = 0.f;
    mp[tid][0] = 0.f;
    mp[tid][65] = 0.f;
  }
  for (int t = tid; t < 64 * 192; t += 256) wwL[t / 192][t % 192] = ww[t];
#pragma unroll
  for (int t4 = tid; t4 < 1024; t4 += 256) {
    f32x4 s = {0.f, 0.f, 0.f, 0.f};
#pragma unroll
    for (int cg = 0; cg < 8; ++cg)
      s += reinterpret_cast<const f32x4*>(f2part +
                                          ((size_t)(cg * NB + b)) * NHW)[t4];
    s *= (1.0f / (float)NC);
    const int r = t4 >> 4;
    const int c = (t4 & 15) * 4;
    mp[1 + r][1 + c + 0] = s.x;
    mp[1 + r][1 + c + 1] = s.y;
    mp[1 + r][1 + c + 2] = s.z;
    mp[1 + r][1 + c + 3] = s.w;
  }
  __syncthreads();

  const int j = tid & 63;                        // lane = output column
  const int iA = rg * 8 + (tid >> 6) * 2;        // wave-uniform row pair
  const int iB = iA + 1;
  const float* whA = wh + 192 * __builtin_amdgcn_readfirstlane(iA);
  const float* whB = whA + 192;
  const float* wwp = &wwL[j][0];
  float accA = 0.f, accB = 0.f;
#pragma unroll 8
  for (int ic = 0; ic < 64; ++ic) {
    const float m0 = mp[ic + 1][j];
    const float m1 = mp[ic + 1][j + 1];
    const float m2 = mp[ic + 1][j + 2];
    accA += whA[ic * 3 + 0] * m0 + whA[ic * 3 + 1] * m1 + whA[ic * 3 + 2] * m2;
    accB += whB[ic * 3 + 0] * m0 + whB[ic * 3 + 1] * m1 + whB[ic * 3 + 2] * m2;
    const float w0 = wwp[ic * 3 + 0];
    const float w1v = wwp[ic * 3 + 1];
    const float w2 = wwp[ic * 3 + 2];
    const float r0 = mp[iA][ic + 1];
    const float r1 = mp[iA + 1][ic + 1];
    const float r2 = mp[iA + 2][ic + 1];
    const float r3 = mp[iA + 3][ic + 1];
    accA += w0 * r0 + w1v * r1 + w2 * r2;
    accB += w0 * r1 + w1v * r2 + w2 * r3;
  }
  f2raw[(size_t)b * NHW + (iA << 6) + j] = accA;
  f2raw[(size_t)b * NHW + (iB << 6) + j] = accB;

  float lsum = accA + accB;
  float lsq = accA * accA + accB * accB;
#pragma unroll
  for (int off = 32; off > 0; off >>= 1) {
    lsum += __shfl_down(lsum, off);
    lsq += __shfl_down(lsq, off);
  }
  if ((tid & 63) == 0) {
    red[(tid >> 6) * 2 + 0] = lsum;
    red[(tid >> 6) * 2 + 1] = lsq;
  }
  __syncthreads();
  if (tid == 0) {
    bnpart[blockIdx.x * 2 + 0] = red[0] + red[2] + red[4] + red[6];
    bnpart[blockIdx.x * 2 + 1] = red[1] + red[3] + red[5] + red[7];
  }

  if (rg == 0) {
#pragma unroll
    for (int c0 = 0; c0 < 512; c0 += 256) {
      const int c = c0 + tid;
      float acc5 = 0.f;
#pragma unroll
      for (int k = 0; k < 5; ++k) {
        const int cc = c + k - 2;
        if (cc >= 0 && cc < NC) {
          const f32x4* sp = reinterpret_cast<const f32x4*>(
              s1part + (size_t)(b * NC + cc) * 16);
          const f32x4 a = (sp[0] + sp[1]) + (sp[2] + sp[3]);
          acc5 += w1[k] * ((a.x + a.y) + (a.z + a.w));
        }
      }
      acc5 *= (1.0f / (float)NHW);
      f1sig[b * NC + c] = 1.0f / (1.0f + __expf(-acc5));
    }
  }
}

// ---------------------------------------------------------------------------
// Kernel C: out = x * f1sig[b,c] * sig2[b,hw], region-mirrored to k_reduce.
// Per thread: ONE f2raw float4 -> 4 sigmoids total, 16 wave-uniform f1
// scalars, 16 x-loads + 16 nt-stores. Reverse dispatch in groups of 8.
__global__ __launch_bounds__(256) void k_out(const float* __restrict__ x,
                                             const float* __restrict__ f1sig,
                                             const float* __restrict__ f2raw,
                                             const float* __restrict__ bnpart,
                                             const float* __restrict__ gamma,
                                             const float* __restrict__ beta,
                                             float* __restrict__ out) {
  __shared__ float bnv[2];
  const int tid = threadIdx.x;
  if (tid < 64) {
    float s = 0.f, q = 0.f;
#pragma unroll
    for (int r = 0; r < 4; ++r) {
      s += bnpart[2 * (tid + 64 * r) + 0];
      q += bnpart[2 * (tid + 64 * r) + 1];
    }
#pragma unroll
    for (int off = 32; off > 0; off >>= 1) {
      s += __shfl_down(s, off);
      q += __shfl_down(q, off);
    }
    if (tid == 0) {
      const float N = (float)(NB * NHW);
      const float mu = s / N;
      const float var = q / N - mu * mu;
      bnv[0] = mu;
      bnv[1] = gamma[0] * rsqrtf(var + 1e-5f);
    }
  }
  __syncthreads();
  const float mu = bnv[0];
  const float g = bnv[1];
  const float bt = beta[0];

  // reverse dispatch in groups of 8: same bid%8 (XCD), descending globally
  const int grp = blockIdx.x >> 3;
  const int bid = (511 - grp) * 8 + (blockIdx.x & 7);
  const int jc = bid & 15;
  const int cg = (bid >> 4) & 7;
  const int b = bid >> 7;
  const int lane = tid & 63;
  const int wv = tid >> 6;

  const int px = jc * 256 + lane * 4;
  const f32x4 fv = *reinterpret_cast<const f32x4*>(f2raw + b * NHW + px);
  f32x4 s2;
  s2.x = 1.0f / (1.0f + __expf(-(g * (fv.x - mu) + bt)));
  s2.y = 1.0f / (1.0f + __expf(-(g * (fv.y - mu) + bt)));
  s2.z = 1.0f / (1.0f + __expf(-(g * (fv.z - mu) + bt)));
  s2.w = 1.0f / (1.0f + __expf(-(g * (fv.w - mu) + bt)));

  const int cbase = __builtin_amdgcn_readfirstlane(b * NC + cg * 64 + wv * 16);
  float f1v[16];
#pragma unroll
  for (int k = 0; k < 16; ++k) f1v[k] = f1sig[cbase + k];

  const size_t base = (size_t)cbase * NHW + px;
#pragma unroll
  for (int k = 0; k < 16; ++k) {
    const f32x4 xv = *reinterpret_cast<const f32x4*>(x + base + (size_t)k * NHW);
    const f32x4 ov = xv * (s2 * f1v[k]);
    __builtin_nontemporal_store(
        ov, reinterpret_cast<f32x4*>(out + base + (size_t)k * NHW));
  }
}

// ---------------------------------------------------------------------------
extern "C" void kernel_launch(void* const* d_in, const int* in_sizes, int n_in,
                              void* d_out, int out_size, void* d_ws,
                              size_t ws_size, hipStream_t stream) {
  const float* x = (const float*)d_in[0];
  const float* w1 = (const float*)d_in[1];
  const float* wh = (const float*)d_in[2];
  const float* ww = (const float*)d_in[3];
  const float* gamma = (const float*)d_in[4];
  const float* beta = (const float*)d_in[5];
  float* out = (float*)d_out;
  float* ws = (float*)d_ws;

  float* s1part = ws + OFF_S1PART;
  float* f2part = ws + OFF_F2PART;
  float* f1sig = ws + OFF_F1SIG;
  float* f2raw = ws + OFF_F2RAW;
  float* bnpart = ws + OFF_BNPART;

  k_reduce<<<NB * 8 * 16, 256, 0, stream>>>(x, s1part, f2part);
  k_f2<<<NB * 8, 256, 0, stream>>>(f2part, s1part, w1, wh, ww, f2raw, bnpart,
                                   f1sig);
  k_out<<<NB * 8 * 16, 256, 0, stream>>>(x, f1sig, f2raw, bnpart, gamma, beta,
                                         out);
}

// Round 11
// 145.347 us; speedup vs baseline: 1.4919x; 1.0003x over previous
//
#include <hip/hip_runtime.h>

// x [B=32, C=512, H=64, W=64] fp32
#define NB 32
#define NC 512
#define NH 64
#define NW 64
#define NHW 4096
#define NTOT ((size_t)NB * NC * NHW)

typedef float f32x4 __attribute__((ext_vector_type(4)));

// workspace float offsets (every region fully rewritten each launch)
#define OFF_S1PART 0              // [B][C][8jc2]       = 131072
#define OFF_F2PART 131072         // [8cg][B][4096pix]  = 1048576
#define OFF_F1SIG  1179648        // [B][C]             = 16384
#define OFF_F2RAW  1196032        // [B][4096]          = 131072
#define OFF_BNPART 1327104        // [256 blocks][2]    = 512

// ---------------------------------------------------------------------------
// Kernel A: ordered-sweep reduction pass over x, atomic-free.
//   s1part[b,c,jc2]  = sum over the jc2-th 512-pixel chunk of x[b,c,:]
//   f2part[cg,b,pix] = sum over the cg-th 64-channel group of x[b,:,pix]
// grid = 2048 blocks: bid = b*64 + cg*8 + jc2 (b high bits -> ascending
// drain for the L3 tail). Block = 64 ch x 512 px = 128 KB of x; per channel
// each lane loads two consecutive float4s -> each wave reads 2 KB contiguous
// per row (DRAM page locality), and the LDS-transpose epilogue is amortized
// over 2x the data vs R10. launch_bounds(256,4) caps VGPR at 128 so the
// LDS-limited 6 blocks/CU actually fit.
__global__ __launch_bounds__(256, 4) void k_reduce(const float* __restrict__ x,
                                                   float* __restrict__ s1part,
                                                   float* __restrict__ f2part) {
  __shared__ float sbuf[4][16][65];
  __shared__ f32x4 comb[4][128];
  const int bid = blockIdx.x;
  const int jc2 = bid & 7;
  const int cg = (bid >> 3) & 7;
  const int b = bid >> 6;
  const int tid = threadIdx.x;
  const int lane = tid & 63;
  const int wv = tid >> 6;

  const size_t base =
      ((size_t)(b * NC + cg * 64 + wv * 16)) * NHW + jc2 * 512 + lane * 4;
  f32x4 pA = {0.f, 0.f, 0.f, 0.f}, pB = pA;
#pragma unroll
  for (int k = 0; k < 16; ++k) {
    const float* xc = x + base + (size_t)k * NHW;
    const f32x4 vA = *reinterpret_cast<const f32x4*>(xc);
    const f32x4 vB = *reinterpret_cast<const f32x4*>(xc + 256);
    pA += vA;
    pB += vB;
    const f32x4 t = vA + vB;
    sbuf[wv][k][lane] = (t.x + t.y) + (t.z + t.w);
  }
  comb[wv][lane] = pA;
  comb[wv][64 + lane] = pB;
  __syncthreads();

  // s1: 4 lanes per channel, each sums 16 of the 64 per-lane partials
  {
    const int c = lane >> 2;  // channel 0..15 within this wave's set
    const int seg = (lane & 3) * 16;
    float t = 0.f;
#pragma unroll
    for (int m = 0; m < 16; ++m) t += sbuf[wv][c][seg + m];
    t += __shfl_xor(t, 1);
    t += __shfl_xor(t, 2);
    if ((lane & 3) == 0)
      s1part[(size_t)(b * NC + cg * 64 + wv * 16 + c) * 8 + jc2] = t;
  }

  if (tid < 128) {
    const f32x4 r =
        (comb[0][tid] + comb[1][tid]) + (comb[2][tid] + comb[3][tid]);
    reinterpret_cast<f32x4*>(f2part)[((size_t)cg * NB + b) * 1024 + jc2 * 128 +
                                     tid] = r;
  }
}

// ---------------------------------------------------------------------------
// Kernel B: spatial attention map + f1sig, fused. 2 outputs/thread.
// grid = 32 b * 8 rowgroups(8 rows) = 256 blocks, 256 thr. (R10 structure;
// s1part read updated to the new [b,c,8] layout.)
__global__ __launch_bounds__(256) void k_f2(const float* __restrict__ f2part,
                                            const float* __restrict__ s1part,
                                            const float* __restrict__ w1,
                                            const float* __restrict__ wh,
                                            const float* __restrict__ ww,
                                            float* __restrict__ f2raw,
                                            float* __restrict__ bnpart,
                                            float* __restrict__ f1sig) {
  __shared__ float mp[66][66];
  __shared__ float wwL[64][193];
  __shared__ float red[8];
  const int b = blockIdx.x >> 3;
  const int rg = blockIdx.x & 7;
  const int tid = threadIdx.x;

  if (tid < 66) {
    mp[0][tid] = 0.f;
    mp[65][tid] = 0.f;
    mp[tid][0] = 0.f;
    mp[tid][65] = 0.f;
  }
  for (int t = tid; t < 64 * 192; t += 256) wwL[t / 192][t % 192] = ww[t];
#pragma unroll
  for (int t4 = tid; t4 < 1024; t4 += 256) {
    f32x4 s = {0.f, 0.f, 0.f, 0.f};
#pragma unroll
    for (int cg = 0; cg < 8; ++cg)
      s += reinterpret_cast<const f32x4*>(f2part +
                                          ((size_t)(cg * NB + b)) * NHW)[t4];
    s *= (1.0f / (float)NC);
    const int r = t4 >> 4;
    const int c = (t4 & 15) * 4;
    mp[1 + r][1 + c + 0] = s.x;
    mp[1 + r][1 + c + 1] = s.y;
    mp[1 + r][1 + c + 2] = s.z;
    mp[1 + r][1 + c + 3] = s.w;
  }
  __syncthreads();

  const int j = tid & 63;                  // lane = output column
  const int iA = rg * 8 + (tid >> 6) * 2;  // wave-uniform row pair
  const int iB = iA + 1;
  const float* whA = wh + 192 * __builtin_amdgcn_readfirstlane(iA);
  const float* whB = whA + 192;
  const float* wwp = &wwL[j][0];
  float accA = 0.f, accB = 0.f;
#pragma unroll 8
  for (int ic = 0; ic < 64; ++ic) {
    const float m0 = mp[ic + 1][j];
    const float m1 = mp[ic + 1][j + 1];
    const float m2 = mp[ic + 1][j + 2];
    accA += whA[ic * 3 + 0] * m0 + whA[ic * 3 + 1] * m1 + whA[ic * 3 + 2] * m2;
    accB += whB[ic * 3 + 0] * m0 + whB[ic * 3 + 1] * m1 + whB[ic * 3 + 2] * m2;
    const float w0 = wwp[ic * 3 + 0];
    const float w1v = wwp[ic * 3 + 1];
    const float w2 = wwp[ic * 3 + 2];
    const float r0 = mp[iA][ic + 1];
    const float r1 = mp[iA + 1][ic + 1];
    const float r2 = mp[iA + 2][ic + 1];
    const float r3 = mp[iA + 3][ic + 1];
    accA += w0 * r0 + w1v * r1 + w2 * r2;
    accB += w0 * r1 + w1v * r2 + w2 * r3;
  }
  f2raw[(size_t)b * NHW + (iA << 6) + j] = accA;
  f2raw[(size_t)b * NHW + (iB << 6) + j] = accB;

  float lsum = accA + accB;
  float lsq = accA * accA + accB * accB;
#pragma unroll
  for (int off = 32; off > 0; off >>= 1) {
    lsum += __shfl_down(lsum, off);
    lsq += __shfl_down(lsq, off);
  }
  if ((tid & 63) == 0) {
    red[(tid >> 6) * 2 + 0] = lsum;
    red[(tid >> 6) * 2 + 1] = lsq;
  }
  __syncthreads();
  if (tid == 0) {
    bnpart[blockIdx.x * 2 + 0] = red[0] + red[2] + red[4] + red[6];
    bnpart[blockIdx.x * 2 + 1] = red[1] + red[3] + red[5] + red[7];
  }

  if (rg == 0) {
#pragma unroll
    for (int c0 = 0; c0 < 512; c0 += 256) {
      const int c = c0 + tid;
      float acc5 = 0.f;
#pragma unroll
      for (int k = 0; k < 5; ++k) {
        const int cc = c + k - 2;
        if (cc >= 0 && cc < NC) {
          const f32x4* sp = reinterpret_cast<const f32x4*>(
              s1part + (size_t)(b * NC + cc) * 8);
          const f32x4 a = sp[0] + sp[1];
          acc5 += w1[k] * ((a.x + a.y) + (a.z + a.w));
        }
      }
      acc5 *= (1.0f / (float)NHW);
      f1sig[b * NC + c] = 1.0f / (1.0f + __expf(-acc5));
    }
  }
}

// ---------------------------------------------------------------------------
// Kernel C: out = x * f1sig[b,c] * sig2[b,hw], region-mirrored to k_reduce's
// R9 decomposition (4096 regions of 64ch x 256px). Per thread: ONE f2raw
// float4 -> 4 sigmoids total, 16 wave-uniform f1 scalars, 16 x-loads +
// 16 nt-stores. Reverse dispatch in groups of 8 (L3 tail first). Unchanged —
// measured at the mixed-stream BW ceiling.
__global__ __launch_bounds__(256) void k_out(const float* __restrict__ x,
                                             const float* __restrict__ f1sig,
                                             const float* __restrict__ f2raw,
                                             const float* __restrict__ bnpart,
                                             const float* __restrict__ gamma,
                                             const float* __restrict__ beta,
                                             float* __restrict__ out) {
  __shared__ float bnv[2];
  const int tid = threadIdx.x;
  if (tid < 64) {
    float s = 0.f, q = 0.f;
#pragma unroll
    for (int r = 0; r < 4; ++r) {
      s += bnpart[2 * (tid + 64 * r) + 0];
      q += bnpart[2 * (tid + 64 * r) + 1];
    }
#pragma unroll
    for (int off = 32; off > 0; off >>= 1) {
      s += __shfl_down(s, off);
      q += __shfl_down(q, off);
    }
    if (tid == 0) {
      const float N = (float)(NB * NHW);
      const float mu = s / N;
      const float var = q / N - mu * mu;
      bnv[0] = mu;
      bnv[1] = gamma[0] * rsqrtf(var + 1e-5f);
    }
  }
  __syncthreads();
  const float mu = bnv[0];
  const float g = bnv[1];
  const float bt = beta[0];

  // reverse dispatch in groups of 8: same bid%8 (XCD), descending globally
  const int grp = blockIdx.x >> 3;
  const int bid = (511 - grp) * 8 + (blockIdx.x & 7);
  const int jc = bid & 15;
  const int cg = (bid >> 4) & 7;
  const int b = bid >> 7;
  const int lane = tid & 63;
  const int wv = tid >> 6;

  const int px = jc * 256 + lane * 4;
  const f32x4 fv = *reinterpret_cast<const f32x4*>(f2raw + b * NHW + px);
  f32x4 s2;
  s2.x = 1.0f / (1.0f + __expf(-(g * (fv.x - mu) + bt)));
  s2.y = 1.0f / (1.0f + __expf(-(g * (fv.y - mu) + bt)));
  s2.z = 1.0f / (1.0f + __expf(-(g * (fv.z - mu) + bt)));
  s2.w = 1.0f / (1.0f + __expf(-(g * (fv.w - mu) + bt)));

  const int cbase = __builtin_amdgcn_readfirstlane(b * NC + cg * 64 + wv * 16);
  float f1v[16];
#pragma unroll
  for (int k = 0; k < 16; ++k) f1v[k] = f1sig[cbase + k];

  const size_t base = (size_t)cbase * NHW + px;
#pragma unroll
  for (int k = 0; k < 16; ++k) {
    const f32x4 xv = *reinterpret_cast<const f32x4*>(x + base + (size_t)k * NHW);
    const f32x4 ov = xv * (s2 * f1v[k]);
    __builtin_nontemporal_store(
        ov, reinterpret_cast<f32x4*>(out + base + (size_t)k * NHW));
  }
}

// ---------------------------------------------------------------------------
extern "C" void kernel_launch(void* const* d_in, const int* in_sizes, int n_in,
                              void* d_out, int out_size, void* d_ws,
                              size_t ws_size, hipStream_t stream) {
  const float* x = (const float*)d_in[0];
  const float* w1 = (const float*)d_in[1];
  const float* wh = (const float*)d_in[2];
  const float* ww = (const float*)d_in[3];
  const float* gamma = (const float*)d_in[4];
  const float* beta = (const float*)d_in[5];
  float* out = (float*)d_out;
  float* ws = (float*)d_ws;

  float* s1part = ws + OFF_S1PART;
  float* f2part = ws + OFF_F2PART;
  float* f1sig = ws + OFF_F1SIG;
  float* f2raw = ws + OFF_F2RAW;
  float* bnpart = ws + OFF_BNPART;

  k_reduce<<<NB * 8 * 8, 256, 0, stream>>>(x, s1part, f2part);
  k_f2<<<NB * 8, 256, 0, stream>>>(f2part, s1part, w1, wh, ww, f2raw, bnpart,
                                   f1sig);
  k_out<<<NB * 8 * 16, 256, 0, stream>>>(x, f1sig, f2raw, bnpart, gamma, beta,
                                         out);
}